// Round 3
// baseline (212.883 us; speedup 1.0000x reference)
//
#include <hip/hip_runtime.h>
#include <hip/hip_bf16.h>

// ---------------------------------------------------------------------------
// InferCellV2 R9: A-from-L2, B-only LDS.
// R6/R8 post-mortem: two different schedules both ~152us because both are
// bound by the same thing: 8 ds_read_b128 per 16 MFMA on the one shared
// LDS pipe (5x oversubscribed -> hard ~20% MfmaUtil ceiling; R7 measured
// conv<3> at 19% of peak = exactly that), at 2 waves/SIMD with barrier-
// chopped dep chains (no latency hiding), plus a chip-wide serial A-staging
// HBM burst per source switch (every CU stalls together - siblings can't
// cover). R9 removes A from LDS: A-frags load straight from global (r-bufs
// are ~2.4MB/XCD/source -> L2-resident; 9-tap + kx-overlap re-reads hit L1).
// Global loads pipeline deep via compiler vmcnt(N) - no barriers, no lgkm
// entanglement (addrspace(1) cast -> global_load, never flat). LDS holds
// only B (9 taps, 73728B) staged once per source from the L2-hot 442KB wt.
// -> LDS demand halves (4 reads / 16 MFMA, ceiling 40%), switch burst gone,
// 2 independent 256-thr blocks/CU desync-cover each other's switches.
// Block 256 thr / 4 waves / 8 out rows; grid 512 = 2 blocks/CU.
// Layouts unchanged (swizzles kept so pre_kernel/epilogues are untouched):
//   activations: zero-padded NHWC bf16 [B][34][34][64], chunk cb of pixel p
//     at p*128 + ((cb^(p&7))*16);  weights wt[l][tap][o][i], chunk i>>3 of
//     row o at slot (i>>3)^(o&7). B staging = linear 16B chunks.
// Wave tile 64px x 64oc = 4x4 MFMA 16x16x32, 64 acc VGPRs.
// ---------------------------------------------------------------------------

typedef __bf16 bf16x8 __attribute__((ext_vector_type(8)));
typedef float floatx4 __attribute__((ext_vector_type(4)));
typedef unsigned int uint32;

#define PADW 34
#define PIMG (PADW * PADW)
#define TAPB (64 * 64 * 2)          // 8192 B per weight tap
#define B_LDS (9 * TAPB)            // 73728 B -> 2 blocks/CU (147.4/160KB)
#define B_CHUNKS (B_LDS / 16)       // 4608 = 18 * 256
#define SMEM_BYTES B_LDS

__device__ __forceinline__ void gld16(const char* g, char* l) {
    __builtin_amdgcn_global_load_lds(
        (const __attribute__((address_space(1))) uint32*)g,
        (__attribute__((address_space(3))) uint32*)l, 16, 0, 0);
}

__device__ __forceinline__ bf16x8 gload8(const char* g) {
    return *(const __attribute__((address_space(1))) bf16x8*)g;
}

// ---------------- fused pre-pass: prep_weights + zero_halo + relu_pad -------
__global__ __launch_bounds__(256) void pre_kernel(
    const float* __restrict__ in, const float* __restrict__ a1,
    const float* __restrict__ a2, const float* __restrict__ W,
    __hip_bfloat16* __restrict__ wt, __hip_bfloat16* __restrict__ r0,
    __hip_bfloat16* __restrict__ r1, __hip_bfloat16* __restrict__ r2) {
    __shared__ float tile[32][65];
    int blk = blockIdx.x;
    int tid = threadIdx.x;

    if (blk < 864) {                 // ---- weights: fold scale + swizzle
        int idx = blk * 256 + tid;   // 6*9*64*64 = 221184 exact
        int i = idx & 63;
        int o = (idx >> 6) & 63;
        int rest = idx >> 12;
        int t = rest % 9;
        int l = rest / 9;
        int ji = i >> 3, jo = o >> 3;
        float ain = 0.f, aout = 0.f;
#pragma unroll
        for (int j = 0; j < 8; ++j) {
            ain  += (j >= ji) ? a1[j] : 0.f;
            aout += (j >= jo) ? a2[j] : 0.f;
        }
        float v = W[(size_t)((l * 64 + o) * 64 + i) * 9 + t] * ain * aout;
        size_t e = (size_t)(l * 9 + t) * 4096 + o * 64 +
                   ((((i >> 3) ^ (o & 7)) << 3) + (i & 7));
        wt[e] = __float2bfloat16(v);
    } else if (blk < 992) {          // ---- zero halo ring, image b
        int b = blk - 864;
        __hip_bfloat16* bufs[3] = {r0, r1, r2};
#pragma unroll
        for (int f = 0; f < 3; ++f) {
            uint32* buf = (uint32*)(bufs[f] + (size_t)b * PIMG * 64);
            for (int idx = tid; idx < 132 * 32; idx += 256) {
                int slot = idx >> 5, u = idx & 31;
                int yy, xx;
                if (slot < 34)      { yy = 0;  xx = slot; }
                else if (slot < 68) { yy = 33; xx = slot - 34; }
                else { int s2 = slot - 68; yy = 1 + (s2 >> 1); xx = (s2 & 1) * 33; }
                buf[(size_t)(yy * PADW + xx) * 32 + u] = 0u;
            }
        }
    } else {                         // ---- relu(x) -> padded swizzled NHWC
        int rb = blk - 992;
        int b = rb >> 5, y = rb & 31;
        int x = tid & 31, c0 = tid >> 5;
        const float* ip = in + ((size_t)b * 64 * 32 + y) * 32 + x;
#pragma unroll
        for (int cc = 0; cc < 8; ++cc) {
            int c = cc * 8 + c0;
            tile[x][c] = fmaxf(ip[(size_t)c * 1024], 0.f);
        }
        __syncthreads();
        // one 16B chunk store per thread: thread = (pixel xq, chunk j);
        // chunk j of pixel p lives at p*128 + (j^(p&7))*16.
        int j = tid & 7, xq = tid >> 3;
        int p = (b * PADW + y + 1) * PADW + 1 + xq;
        alignas(16) __hip_bfloat16 hv[8];
#pragma unroll
        for (int k = 0; k < 8; ++k)
            hv[k] = __float2bfloat16(tile[xq][j * 8 + k]);
        *(uint4*)((char*)r0 + (size_t)p * 128 + ((j ^ (p & 7)) << 4)) =
            *(const uint4*)hv;
    }
}

// ---------------- conv stage: A from L2, B from LDS, no inner barriers -----
// Block: image b = blk>>2, strip y0 = (blk&3)*8. Wave wv (0..3): rows
// y0+2wv, y0+2wv+1.  A-frag: l15 = px, quad+q*4 = in-ch chunk. B-frag:
// l15 = oc. C/D: M(pixel) = quad*4+r.
template <int NSRC, bool FINAL>
__global__ __launch_bounds__(256, 2) void conv_stage(
    const __hip_bfloat16* __restrict__ s0,
    const __hip_bfloat16* __restrict__ s1,
    const __hip_bfloat16* __restrict__ s2,
    const __hip_bfloat16* __restrict__ wt,
    void* __restrict__ dstv, int l0) {
    extern __shared__ char smemB[];              // B only: 73728 B
    int tid = threadIdx.x;
    int wv = tid >> 6, lane = tid & 63;
    int quad = lane >> 4, l15 = lane & 15;
    int blk = blockIdx.x;
    int b = blk >> 2, y0 = (blk & 3) << 3;
    int Rb = b * PADW + y0;          // base padded-row index of this strip

    const char* srcs[3] = {(const char*)s0, (const char*)s1, (const char*)s2};
    const char* gW = (const char*)wt + (size_t)l0 * 9 * (size_t)TAPB;

    auto stage_B = [&](int s) {      // all 9 taps of edge l0+s, 18 chunks/thr
        const char* gB = gW + (size_t)s * 9 * TAPB;
#pragma unroll
        for (int it = 0; it < 18; ++it)
            gld16(gB + (size_t)(it * 256 + tid) * 16,
                  smemB + (it * 256 + wv * 64) * 16);
    };

    floatx4 acc[4][4];
#pragma unroll
    for (int m = 0; m < 4; ++m)
#pragma unroll
        for (int n = 0; n < 4; ++n) acc[m][n] = (floatx4){0.f, 0.f, 0.f, 0.f};

    stage_B(0);
    __syncthreads();                 // B(src0) resident

#pragma unroll 1
    for (int s = 0; s < NSRC; ++s) {
        const char* gA = srcs[s];
#pragma unroll
        for (int tl = 0; tl < 9; ++tl) {
            const int ky = tl / 3, kx = tl % 3;
            // pixel addresses for the 4 m-tiles (q only flips chunk bit 2
            // -> addr XOR 64; compiler folds)
            size_t pp[4];
            int p7[4];
#pragma unroll
            for (int m = 0; m < 4; ++m) {
                int R = Rb + 2 * wv + (m >> 1) + ky;      // padded row
                int apx = ((m & 1) << 4) + l15 + kx;      // 0..33
                int p = R * PADW + apx;                   // linear pad pixel
                pp[m] = (size_t)p * 128;
                p7[m] = p & 7;
            }
#pragma unroll
            for (int q = 0; q < 2; ++q) {
                bf16x8 Af[4], Bf[4];
#pragma unroll
                for (int m = 0; m < 4; ++m) {
                    int slot = ((q << 2) + quad) ^ p7[m];
                    Af[m] = gload8(gA + pp[m] + slot * 16);
                }
#pragma unroll
                for (int n = 0; n < 4; ++n) {
                    int o = (n << 4) + l15;
                    int slot = ((q << 2) + quad) ^ (l15 & 7);
                    Bf[n] = *(const bf16x8*)(smemB + tl * TAPB +
                                             o * 128 + slot * 16);
                }
                __builtin_amdgcn_s_setprio(1);
#pragma unroll
                for (int m = 0; m < 4; ++m)
#pragma unroll
                    for (int n = 0; n < 4; ++n)
                        acc[m][n] = __builtin_amdgcn_mfma_f32_16x16x32_bf16(
                            Af[m], Bf[n], acc[m][n], 0, 0, 0);
                __builtin_amdgcn_s_setprio(0);
            }
        }
        if (s + 1 < NSRC) {          // source switch: B-only, L2-hot (~0.5us;
            __syncthreads();         //  sibling block on this CU desyncs)
            stage_B(s + 1);
            __syncthreads();         // vmcnt drained by barrier
        }
    }

    // Epilogue. M(pixel) = quad*4+r (+16 for odd m-tile), N(oc) = n*16+l15.
    if (FINAL) {
        float* out = (float*)dstv;   // fp32 NCHW [128][64][32][32]
#pragma unroll
        for (int m = 0; m < 4; ++m) {
            int row = y0 + 2 * wv + (m >> 1);
#pragma unroll
            for (int n = 0; n < 4; ++n) {
                int o = (n << 4) + l15;
                *(floatx4*)(out + (((size_t)b * 64 + o) * 32 + row) * 32 +
                            ((m & 1) << 4) + (quad << 2)) = acc[m][n];
            }
        }
    } else {
        __hip_bfloat16* out = (__hip_bfloat16*)dstv;  // relu -> swizzled NHWC
#pragma unroll
        for (int m = 0; m < 4; ++m) {
            int row = y0 + 2 * wv + (m >> 1);
#pragma unroll
            for (int n = 0; n < 4; ++n) {
                int o = (n << 4) + l15;
#pragma unroll
                for (int r = 0; r < 4; ++r) {
                    int x = ((m & 1) << 4) + (quad << 2) + r;
                    int p = (b * PADW + row + 1) * PADW + x + 1;
                    float v = fmaxf(acc[m][n][r], 0.f);
                    size_t e = (size_t)p * 64 +
                               ((((o >> 3) ^ (p & 7)) << 3) + (o & 7));
                    out[e] = __float2bfloat16(v);
                }
            }
        }
    }
}

// ---------------------------------------------------------------------------
extern "C" void kernel_launch(void* const* d_in, const int* in_sizes, int n_in,
                              void* d_out, int out_size, void* d_ws,
                              size_t ws_size, hipStream_t stream) {
    const float* inputs  = (const float*)d_in[0];
    const float* alphas1 = (const float*)d_in[1];
    const float* alphas2 = (const float*)d_in[2];
    const float* W       = (const float*)d_in[3];
    char* ws = (char*)d_ws;

    __hip_bfloat16* wt = (__hip_bfloat16*)(ws);                     // 442 KB
    __hip_bfloat16* r0 = (__hip_bfloat16*)(ws + ((size_t)1 << 20)); // 18.9 MB
    __hip_bfloat16* r1 = (__hip_bfloat16*)(ws + ((size_t)20 << 20));
    __hip_bfloat16* r2 = (__hip_bfloat16*)(ws + ((size_t)40 << 20));
    float* out = (float*)d_out;

    // Opt-in to >64KB dynamic LDS (idempotent; harmless under graph capture).
    (void)hipFuncSetAttribute((const void*)conv_stage<1, false>,
                              hipFuncAttributeMaxDynamicSharedMemorySize,
                              SMEM_BYTES);
    (void)hipFuncSetAttribute((const void*)conv_stage<2, false>,
                              hipFuncAttributeMaxDynamicSharedMemorySize,
                              SMEM_BYTES);
    (void)hipFuncSetAttribute((const void*)conv_stage<3, true>,
                              hipFuncAttributeMaxDynamicSharedMemorySize,
                              SMEM_BYTES);

    pre_kernel<<<864 + 128 + 4096, 256, 0, stream>>>(inputs, alphas1, alphas2,
                                                     W, wt, r0, r1, r2);
    conv_stage<1, false><<<512, 256, SMEM_BYTES, stream>>>(r0, r1, r2, wt,
                                                           (void*)r1, 0);
    conv_stage<2, false><<<512, 256, SMEM_BYTES, stream>>>(r0, r1, r2, wt,
                                                           (void*)r2, 1);
    conv_stage<3, true ><<<512, 256, SMEM_BYTES, stream>>>(r0, r1, r2, wt,
                                                           (void*)out, 3);
}